// Round 1
// baseline (271.721 us; speedup 1.0000x reference)
//
#include <hip/hip_runtime.h>
#include <hip/hip_bf16.h>

typedef __attribute__((ext_vector_type(8))) short short8;
typedef __attribute__((ext_vector_type(4))) float float4v;

using bf16 = __hip_bfloat16;

__device__ inline short f2bf(float f) {
  __hip_bfloat16 h = __float2bfloat16(f);
  short s;
  __builtin_memcpy(&s, &h, 2);
  return s;
}

__device__ inline float4v mfma16(short8 a, short8 b, float4v c) {
  return __builtin_amdgcn_mfma_f32_16x16x32_bf16(a, b, c, 0, 0, 0);
}

// ---------------- conversion kernels ----------------

__global__ __launch_bounds__(256) void conv_x_kernel(const float* __restrict__ x,
                                                     bf16* __restrict__ xb) {
  int i = blockIdx.x * 256 + threadIdx.x;
  const float4v* src = reinterpret_cast<const float4v*>(x);
  float4v a = src[(size_t)i * 2];
  float4v c = src[(size_t)i * 2 + 1];
  short8 o;
  o[0] = f2bf(a[0]); o[1] = f2bf(a[1]); o[2] = f2bf(a[2]); o[3] = f2bf(a[3]);
  o[4] = f2bf(c[0]); o[5] = f2bf(c[1]); o[6] = f2bf(c[2]); o[7] = f2bf(c[3]);
  *reinterpret_cast<short8*>(xb + (size_t)i * 8) = o;
}

// Wt[z][n][k] = W_z[k][n]  (bf16), LDS-tiled transpose
__global__ void conv_w_kernel(const float* __restrict__ Wq, const float* __restrict__ Wk,
                              const float* __restrict__ Wv, bf16* __restrict__ wt) {
  __shared__ float tile[32][33];
  int z = blockIdx.z;
  const float* W = (z == 0) ? Wq : (z == 1) ? Wk : Wv;
  int n = blockIdx.x * 32 + threadIdx.x;
  int k = blockIdx.y * 32 + threadIdx.y;
  tile[threadIdx.y][threadIdx.x] = W[(size_t)k * 512 + n];
  __syncthreads();
  int nn = blockIdx.x * 32 + threadIdx.y;
  int kk = blockIdx.y * 32 + threadIdx.x;
  wt[(size_t)z * 512 * 512 + (size_t)nn * 512 + kk] = __float2bfloat16(tile[threadIdx.x][threadIdx.y]);
}

// ---------------- QKV projection GEMM ----------------
// C[m][n] = sum_k X[m][k] * W[k][n] + bias[n]
// Q,K stored [b,h,S,64]; V stored transposed [b,h,64,S].

__global__ __launch_bounds__(256) void qkv_gemm_kernel(
    const bf16* __restrict__ xb, const bf16* __restrict__ wt,
    const float* __restrict__ bq, const float* __restrict__ bk, const float* __restrict__ bv,
    bf16* __restrict__ qb, bf16* __restrict__ kbuf, bf16* __restrict__ vt) {
  __shared__ bf16 Xs[64][72];
  __shared__ bf16 Ws[64][72];
  const int m0 = blockIdx.x * 64;
  const int n0 = blockIdx.y * 64;
  const int z  = blockIdx.z;
  const bf16* W = wt + (size_t)z * 512 * 512;
  const float* bias = (z == 0) ? bq : (z == 1) ? bk : bv;
  const int t = threadIdx.x;
  const int lane = t & 63, wv = t >> 6;
  const int row = t >> 3, col8 = (t & 7) * 8;
  const int lo = lane & 15, g8 = (lane >> 4) * 8;
  float4v acc[4] = {};
  for (int k0 = 0; k0 < 512; k0 += 64) {
    *reinterpret_cast<short8*>(&Xs[row][col8])      = *reinterpret_cast<const short8*>(&xb[(size_t)(m0 + row) * 512 + k0 + col8]);
    *reinterpret_cast<short8*>(&Xs[row + 32][col8]) = *reinterpret_cast<const short8*>(&xb[(size_t)(m0 + row + 32) * 512 + k0 + col8]);
    *reinterpret_cast<short8*>(&Ws[row][col8])      = *reinterpret_cast<const short8*>(&W[(size_t)(n0 + row) * 512 + k0 + col8]);
    *reinterpret_cast<short8*>(&Ws[row + 32][col8]) = *reinterpret_cast<const short8*>(&W[(size_t)(n0 + row + 32) * 512 + k0 + col8]);
    __syncthreads();
    short8 a0 = *reinterpret_cast<const short8*>(&Xs[wv * 16 + lo][g8]);
    short8 a1 = *reinterpret_cast<const short8*>(&Xs[wv * 16 + lo][32 + g8]);
#pragma unroll
    for (int nt = 0; nt < 4; ++nt) {
      short8 b0 = *reinterpret_cast<const short8*>(&Ws[nt * 16 + lo][g8]);
      short8 b1 = *reinterpret_cast<const short8*>(&Ws[nt * 16 + lo][32 + g8]);
      acc[nt] = mfma16(a0, b0, acc[nt]);
      acc[nt] = mfma16(a1, b1, acc[nt]);
    }
    __syncthreads();
  }
#pragma unroll
  for (int nt = 0; nt < 4; ++nt) {
    int ncol = n0 + nt * 16 + lo;
    float bias_v = bias[ncol];
    int h = ncol >> 6, d = ncol & 63;
#pragma unroll
    for (int r = 0; r < 4; ++r) {
      int mrow = m0 + wv * 16 + (lane >> 4) * 4 + r;
      int bb = mrow >> 12, s = mrow & 4095;
      bf16 o = __float2bfloat16(acc[nt][r] + bias_v);
      if (z == 0)      qb[((size_t)(bb * 8 + h) * 4096 + s) * 64 + d] = o;
      else if (z == 1) kbuf[((size_t)(bb * 8 + h) * 4096 + s) * 64 + d] = o;
      else             vt[((size_t)(bb * 8 + h) * 64 + d) * 4096 + s] = o;
    }
  }
}

// ---------------- flash attention ----------------
// grid (S/64, B*NH); block 256 = 4 waves; wave handles 16 q rows.

__global__ __launch_bounds__(256) void attn_kernel(
    const bf16* __restrict__ qbuf, const bf16* __restrict__ kbuf,
    const bf16* __restrict__ vtbuf, float* __restrict__ out) {
  __shared__ bf16 Ks[64][72];
  __shared__ bf16 Vs[64][72];
  __shared__ bf16 Ps[4][16][72];
  const int qt = blockIdx.x, bh = blockIdx.y;
  const int bI = bh >> 3, h = bh & 7;
  const int t = threadIdx.x, lane = t & 63, wv = t >> 6;
  const int lo = lane & 15, g8 = (lane >> 4) * 8;
  const int row = t >> 3, col8 = (t & 7) * 8;
  const bf16* qbase = qbuf + (size_t)bh * 4096 * 64;
  const bf16* kbase = kbuf + (size_t)bh * 4096 * 64;
  const bf16* vbase = vtbuf + (size_t)bh * 64 * 4096;
  const int q0 = qt * 64;
  short8 qf0 = *reinterpret_cast<const short8*>(&qbase[(size_t)(q0 + wv * 16 + lo) * 64 + g8]);
  short8 qf1 = *reinterpret_cast<const short8*>(&qbase[(size_t)(q0 + wv * 16 + lo) * 64 + 32 + g8]);
  float m_run[4], l_run[4];
  float4v oacc[4] = {};
#pragma unroll
  for (int r = 0; r < 4; ++r) { m_run[r] = -1e30f; l_run[r] = 0.f; }
  for (int kk0 = 0; kk0 < 4096; kk0 += 64) {
    *reinterpret_cast<short8*>(&Ks[row][col8])      = *reinterpret_cast<const short8*>(&kbase[(size_t)(kk0 + row) * 64 + col8]);
    *reinterpret_cast<short8*>(&Ks[row + 32][col8]) = *reinterpret_cast<const short8*>(&kbase[(size_t)(kk0 + row + 32) * 64 + col8]);
    *reinterpret_cast<short8*>(&Vs[row][col8])      = *reinterpret_cast<const short8*>(&vbase[(size_t)row * 4096 + kk0 + col8]);
    *reinterpret_cast<short8*>(&Vs[row + 32][col8]) = *reinterpret_cast<const short8*>(&vbase[(size_t)(row + 32) * 4096 + kk0 + col8]);
    __syncthreads();
    float4v sacc[4];
    float4v zero = {0.f, 0.f, 0.f, 0.f};
#pragma unroll
    for (int kt = 0; kt < 4; ++kt) {
      short8 b0 = *reinterpret_cast<const short8*>(&Ks[kt * 16 + lo][g8]);
      short8 b1 = *reinterpret_cast<const short8*>(&Ks[kt * 16 + lo][32 + g8]);
      sacc[kt] = mfma16(qf0, b0, zero);
      sacc[kt] = mfma16(qf1, b1, sacc[kt]);
    }
#pragma unroll
    for (int kt = 0; kt < 4; ++kt)
#pragma unroll
      for (int r = 0; r < 4; ++r) sacc[kt][r] *= 0.125f;
    float mnew[4], scal[4], lt[4];
#pragma unroll
    for (int r = 0; r < 4; ++r) {
      float v = fmaxf(fmaxf(sacc[0][r], sacc[1][r]), fmaxf(sacc[2][r], sacc[3][r]));
#pragma unroll
      for (int mm = 1; mm < 16; mm <<= 1) v = fmaxf(v, __shfl_xor(v, mm));
      mnew[r] = fmaxf(m_run[r], v);
      scal[r] = __expf(m_run[r] - mnew[r]);
      m_run[r] = mnew[r];
      lt[r] = 0.f;
    }
#pragma unroll
    for (int kt = 0; kt < 4; ++kt)
#pragma unroll
      for (int r = 0; r < 4; ++r) {
        float p = __expf(sacc[kt][r] - mnew[r]);
        sacc[kt][r] = p;
        lt[r] += p;
      }
#pragma unroll
    for (int r = 0; r < 4; ++r) {
#pragma unroll
      for (int mm = 1; mm < 16; mm <<= 1) lt[r] += __shfl_xor(lt[r], mm);
      l_run[r] = l_run[r] * scal[r] + lt[r];
    }
#pragma unroll
    for (int dt = 0; dt < 4; ++dt)
#pragma unroll
      for (int r = 0; r < 4; ++r) oacc[dt][r] *= scal[r];
    // P -> wave-private LDS (D-layout scatter), then re-read as A-fragments
#pragma unroll
    for (int kt = 0; kt < 4; ++kt)
#pragma unroll
      for (int r = 0; r < 4; ++r)
        Ps[wv][(lane >> 4) * 4 + r][kt * 16 + lo] = __float2bfloat16(sacc[kt][r]);
    short8 pf0 = *reinterpret_cast<const short8*>(&Ps[wv][lo][g8]);
    short8 pf1 = *reinterpret_cast<const short8*>(&Ps[wv][lo][32 + g8]);
#pragma unroll
    for (int dt = 0; dt < 4; ++dt) {
      short8 v0 = *reinterpret_cast<const short8*>(&Vs[dt * 16 + lo][g8]);
      short8 v1 = *reinterpret_cast<const short8*>(&Vs[dt * 16 + lo][32 + g8]);
      oacc[dt] = mfma16(pf0, v0, oacc[dt]);
      oacc[dt] = mfma16(pf1, v1, oacc[dt]);
    }
    __syncthreads();
  }
#pragma unroll
  for (int dt = 0; dt < 4; ++dt)
#pragma unroll
    for (int r = 0; r < 4; ++r) {
      int s = q0 + wv * 16 + (lane >> 4) * 4 + r;
      int d = dt * 16 + lo;
      out[((size_t)bI * 4096 + s) * 512 + h * 64 + d] = oacc[dt][r] / l_run[r];
    }
}

// ---------------- launch ----------------

extern "C" void kernel_launch(void* const* d_in, const int* in_sizes, int n_in,
                              void* d_out, int out_size, void* d_ws, size_t ws_size,
                              hipStream_t stream) {
  const float* x  = (const float*)d_in[0];
  const float* Wq = (const float*)d_in[1];
  const float* bq = (const float*)d_in[2];
  const float* Wk = (const float*)d_in[3];
  const float* bk = (const float*)d_in[4];
  const float* Wv = (const float*)d_in[5];
  const float* bv = (const float*)d_in[6];
  float* out = (float*)d_out;

  char* ws = (char*)d_ws;
  // B*S*H = 8192*512
  bf16* xb = (bf16*)(ws + 0);                    // 8,388,608 B
  bf16* wt = (bf16*)(ws + 8388608);              // 1,572,864 B
  bf16* qb = (bf16*)(ws + 9961472);              // 8,388,608 B
  bf16* kb = (bf16*)(ws + 18350080);             // 8,388,608 B
  bf16* vt = (bf16*)(ws + 26738688);             // 8,388,608 B -> total 35,127,296 B

  conv_x_kernel<<<2048, 256, 0, stream>>>(x, xb);
  conv_w_kernel<<<dim3(16, 16, 3), dim3(32, 32), 0, stream>>>(Wq, Wk, Wv, wt);
  qkv_gemm_kernel<<<dim3(128, 8, 3), 256, 0, stream>>>(xb, wt, bq, bk, bv, qb, kb, vt);
  attn_kernel<<<dim3(64, 16), 256, 0, stream>>>(qb, kb, vt, out);
}